// Round 1
// baseline (19217.990 us; speedup 1.0000x reference)
//
#include <hip/hip_runtime.h>
#include <stdint.h>
#include <math.h>

#define HH   512
#define BB   64
#define TT   2000
#define NEXC 409   // int(0.8 * 512) = int(409.6)

// Python-float constants, rounded to f32 exactly as the reference does.
constexpr float ALPHA_F     = 0.1f;                          // DT/TAU, weak-typed to f32
constexpr float IN_SCALE_F  = (float)4.4721359549995794e-03; // sqrt(2*(DT/TAU)*SIG_IN^2)
constexpr float REC_SCALE_F = (float)4.4721359549995794e-02; // sqrt(2*(TAU/DT)*SIG_REC^2)
constexpr float SQRT2_F     = 1.41421356237309515f;          // np.sqrt(2) -> f32
constexpr float U_LO        = -0x1.fffffep-1f;               // nextafter(-1, 0)

struct U2 { uint32_t a, b; };

__host__ __device__ constexpr uint32_t rotl32(uint32_t x, int d) {
  return (x << d) | (x >> (32 - d));
}

// JAX Threefry-2x32, 20 rounds.
__host__ __device__ constexpr U2 tf2x32(uint32_t k0, uint32_t k1,
                                        uint32_t x0, uint32_t x1) {
  uint32_t ks[3] = {k0, k1, k0 ^ k1 ^ 0x1BD11BDAu};
  const int R[2][4] = {{13, 15, 26, 6}, {17, 29, 16, 24}};
  x0 += ks[0]; x1 += ks[1];
  for (int g = 0; g < 5; ++g) {
    const int* r = R[g & 1];
    for (int i = 0; i < 4; ++i) { x0 += x1; x1 = rotl32(x1, r[i]); x1 ^= x0; }
    x0 += ks[(g + 1) % 3];
    x1 += ks[(g + 2) % 3] + (uint32_t)(g + 1);
  }
  return U2{x0, x1};
}

// fold_in(key(42), d) == cipher((0,42), (0,d))  [threefry_seed(42) = (0,42)]
constexpr U2 KIN_  = tf2x32(0u, 42u, 0u, 0u);
constexpr U2 KREC_ = tf2x32(0u, 42u, 0u, 1u);
constexpr uint32_t KIN0 = KIN_.a,  KIN1 = KIN_.b;
constexpr uint32_t KRC0 = KREC_.a, KRC1 = KREC_.b;

// jax.random.normal element: partitionable threefry (JAX >= 0.4.30 default):
// bits[i] = o1 ^ o2 with counts (hi=0, lo=i); uniform in [lo,1); sqrt2*erfinv.
__device__ __forceinline__ float jax_normal(uint32_t k0, uint32_t k1, uint32_t idx) {
  U2 o = tf2x32(k0, k1, 0u, idx);
  uint32_t bits = o.a ^ o.b;
  float f = __uint_as_float((bits >> 9) | 0x3f800000u) - 1.0f;  // [0,1)
  float u = fmaxf(U_LO, f * 2.0f + U_LO);                       // (hi-lo) rounds to 2.0f
  // XLA ErfInv f32 (Giles), w = -log1p(-u*u)
  float w = -log1pf(-u * u);
  float p;
  if (w < 5.0f) {
    w = w - 2.5f;
    p =             2.81022636e-08f;
    p = fmaf(p, w,  3.43273939e-07f);
    p = fmaf(p, w, -3.5233877e-06f);
    p = fmaf(p, w, -4.39150654e-06f);
    p = fmaf(p, w,  0.00021858087f);
    p = fmaf(p, w, -0.00125372503f);
    p = fmaf(p, w, -0.00417768164f);
    p = fmaf(p, w,  0.246640727f);
    p = fmaf(p, w,  1.50140941f);
  } else {
    w = sqrtf(w) - 3.0f;
    p =            -0.000200214257f;
    p = fmaf(p, w,  0.000100950558f);
    p = fmaf(p, w,  0.00134934322f);
    p = fmaf(p, w, -0.00367342844f);
    p = fmaf(p, w,  0.00573950773f);
    p = fmaf(p, w, -0.0076224613f);
    p = fmaf(p, w,  0.00943887047f);
    p = fmaf(p, w,  1.00167406f);
    p = fmaf(p, w,  2.83297682f);
  }
  return SQRT2_F * (p * u);
}

// wt[i*H + j] = w_hh_ei[j][i] = |w_hh[j,i]| * (i!=j) * ei[i]   (transposed for
// coalesced column reads in the recurrent matvec)
__global__ void prep_wt(const float* __restrict__ whh, float* __restrict__ wt) {
  int idx = blockIdx.x * blockDim.x + threadIdx.x;  // i*H + j
  int i = idx >> 9;
  int j = idx & (HH - 1);
  float v = (i == j) ? 0.0f : fabsf(whh[j * HH + i]);
  wt[idx] = (i < NEXC) ? v : -v;
}

__global__ __launch_bounds__(512, 1)
void zrnn_main(const float* __restrict__ i_stim, const float* __restrict__ i_cc,
               const float* __restrict__ hidden0,
               const float* __restrict__ w_ih, const float* __restrict__ b_hh,
               const float* __restrict__ w_ho, const float* __restrict__ b_ho,
               const float* __restrict__ wt,
               float* __restrict__ outs, float* __restrict__ hids) {
  const int b = blockIdx.x;   // batch
  const int j = threadIdx.x;  // hidden unit owned by this thread

  __shared__ float rh[HH];        // relu(h) broadcast buffer
  __shared__ float stim_s[TT];
  __shared__ float cc_s[TT];
  __shared__ float cur_s[2];
  __shared__ float red[8];

  // Preload this batch's input streams (16 KB LDS), coalesced.
  for (int t = j; t < TT; t += HH) {
    stim_s[t] = i_stim[b * TT + t];
    cc_s[t]   = i_cc[b * TT + t];
  }

  float h = hidden0[b * HH + j];
  const float wih0 = w_ih[j * 2 + 0];
  const float wih1 = w_ih[j * 2 + 1];
  const float bhh  = b_hh[j];
  const float who  = w_ho[j];
  const float bho  = b_ho[0];
  float* __restrict__ hid_out = hids + (size_t)b * TT * HH;

  __syncthreads();

  for (int t = 0; t < TT; ++t) {
    // Stage relu(h) and input current for this step.
    rh[j] = fmaxf(h, 0.0f);
    if (j < 2) {
      uint32_t nidx = (uint32_t)(t * (BB * 2) + b * 2 + j);  // n_in (T,B,I) flat
      float ni = jax_normal(KIN0, KIN1, nidx);
      float x  = (j == 0) ? stim_s[t] : cc_s[t];
      cur_s[j] = fmaxf(x + IN_SCALE_F * ni, 0.0f);
    }
    __syncthreads();

    // hid_hid[j] = sum_i relu(h[i]) * w_hh_ei[j,i]  (wt column j, coalesced)
    float acc = 0.0f;
    #pragma unroll 32
    for (int i = 0; i < HH; ++i) {
      acc = fmaf(rh[i], wt[i * HH + j], acc);
    }

    uint32_t ridx = (uint32_t)t * (uint32_t)(BB * HH) + (uint32_t)(b * HH + j);
    float nr = jax_normal(KRC0, KRC1, ridx);
    float hid_hid = acc + bhh + REC_SCALE_F * nr;
    float hid_in  = cur_s[0] * wih0 + cur_s[1] * wih1;
    h = h + (-h + hid_in + hid_hid) * ALPHA_F;

    __builtin_nontemporal_store(h, hid_out + (size_t)t * HH + j);

    // out[b,t] = relu(h) . w_ho + b_ho  (wave shuffle + LDS reduce)
    float v = fmaxf(h, 0.0f) * who;
    for (int off = 32; off > 0; off >>= 1) v += __shfl_down(v, off);
    if ((j & 63) == 0) red[j >> 6] = v;
    __syncthreads();  // also orders rh reads (this step) vs rh writes (next step)
    if (j == 0) {
      float s = ((red[0] + red[1]) + (red[2] + red[3])) +
                ((red[4] + red[5]) + (red[6] + red[7]));
      outs[b * TT + t] = s + bho;
    }
  }
}

extern "C" void kernel_launch(void* const* d_in, const int* in_sizes, int n_in,
                              void* d_out, int out_size, void* d_ws, size_t ws_size,
                              hipStream_t stream) {
  const float* i_stim = (const float*)d_in[0];
  const float* i_cc   = (const float*)d_in[1];
  const float* hidden = (const float*)d_in[2];
  const float* w_ih   = (const float*)d_in[3];
  // d_in[4] = b_ih — never used by the reference
  const float* w_hh   = (const float*)d_in[5];
  const float* b_hh   = (const float*)d_in[6];
  const float* w_ho   = (const float*)d_in[7];
  const float* b_ho   = (const float*)d_in[8];

  float* outs = (float*)d_out;                       // [B,T,O] = 128000 floats
  float* hids = (float*)d_out + (size_t)BB * TT;     // [B,T,H]
  float* wt   = (float*)d_ws;                        // H*H f32 = 1 MB scratch

  prep_wt<<<(HH * HH) / 256, 256, 0, stream>>>(w_hh, wt);
  zrnn_main<<<BB, HH, 0, stream>>>(i_stim, i_cc, hidden, w_ih, b_hh,
                                   w_ho, b_ho, wt, outs, hids);
}